// Round 1
// baseline (543.388 us; speedup 1.0000x reference)
//
#include <hip/hip_runtime.h>
#include <math.h>

#define RES 64
#define IN_HW 56
#define K_KP 17
#define N_ROWS 4096
#define N_CLS 91
#define R_ROIS 1024
#define SMOOTH_BETA (1.0f / 9.0f)

// Output layout (fp32 flat):
//   [0]                      cls_loss
//   [1]                      box_loss
//   [2 .. 2+52224)           xy_preds  (1024,17,3)
//   [52226 .. 52226+17408)   end_scores (1024,17)
//   [69634 .. 69634+802816)  mask_prob (1024,1,28,28)

__device__ __forceinline__ float keys_cubic(float x) {
    x = fabsf(x);
    if (x < 1.f) return ((1.5f * x - 2.5f) * x) * x + 1.f;
    if (x < 2.f) return ((-0.5f * x + 2.5f) * x - 4.f) * x + 2.f;
    return 0.f;
}

// ---------------- losses: 1 wave per row, 4 rows per block ----------------
__global__ __launch_bounds__(256) void loss_kernel(
    const float* __restrict__ logits, const float* __restrict__ boxreg,
    const int* __restrict__ labels, const float* __restrict__ tgt,
    float* __restrict__ out)
{
    __shared__ float s_cls[4], s_box[4];
    const int tid = threadIdx.x, wv = tid >> 6, ln = tid & 63;
    const int row = blockIdx.x * 4 + wv;

    float cls_p = 0.f, box_p = 0.f;
    {
        const float* lr = logits + (size_t)row * N_CLS;
        float a = (ln < N_CLS) ? lr[ln] : -INFINITY;
        float b = (ln + 64 < N_CLS) ? lr[ln + 64] : -INFINITY;
        float m = fmaxf(a, b);
        #pragma unroll
        for (int off = 32; off; off >>= 1) m = fmaxf(m, __shfl_down(m, off));
        m = __shfl(m, 0);
        float e = 0.f;
        if (ln < N_CLS) e += expf(a - m);
        if (ln + 64 < N_CLS) e += expf(b - m);
        #pragma unroll
        for (int off = 32; off; off >>= 1) e += __shfl_down(e, off);
        if (ln == 0) {
            float lsm = m + logf(e);
            int lbl = labels[row];
            cls_p = lsm - lr[lbl];
            // smooth L1 box loss on the selected class
            const float* sel = boxreg + (size_t)row * (4 * N_CLS) + lbl * 4;
            const float* tg = tgt + (size_t)row * 4;
            float s = 0.f;
            #pragma unroll
            for (int j = 0; j < 4; ++j) {
                float d = sel[j] - tg[j];
                float ad = fabsf(d);
                s += (ad < SMOOTH_BETA) ? (0.5f * d * d / SMOOTH_BETA)
                                        : (ad - 0.5f * SMOOTH_BETA);
            }
            box_p = (lbl > 0) ? s : 0.f;
            s_cls[wv] = cls_p;
            s_box[wv] = box_p;
        }
    }
    __syncthreads();
    if (tid == 0) {
        float c = s_cls[0] + s_cls[1] + s_cls[2] + s_cls[3];
        float b = s_box[0] + s_box[1] + s_box[2] + s_box[3];
        atomicAdd(&out[0], c * (1.f / (float)N_ROWS));
        atomicAdd(&out[1], b * (1.f / (float)N_ROWS));
    }
}

// ------------- keypoints: 1 block per (r,k) map; bicubic 56->64 + argmax -------------
__global__ __launch_bounds__(256) void kp_kernel(
    const float* __restrict__ maps, const float* __restrict__ rois,
    float* __restrict__ out)
{
    __shared__ float sm_in[IN_HW * IN_HW];   // 3136 floats
    __shared__ float sm_tmp[IN_HW * RES];    // 3584 floats (horizontal pass result)
    __shared__ float s_w[RES * 4];
    __shared__ int   s_i[RES * 4];
    __shared__ float s_red_v[4];
    __shared__ int   s_red_i[4];

    const int map_id = blockIdx.x;           // r*17 + k
    const int tid = threadIdx.x;

    // stage the 56x56 map into LDS (float4 coalesced; 3136 % 4 == 0, base 16B-aligned)
    {
        const float4* src = (const float4*)(maps + (size_t)map_id * (IN_HW * IN_HW));
        float4* dst = (float4*)sm_in;
        for (int i = tid; i < (IN_HW * IN_HW) / 4; i += 256) dst[i] = src[i];
    }

    // bicubic weights, identical for both dims (JAX: half-pixel centers, Keys a=-0.5,
    // out-of-range taps dropped, renormalized over valid taps)
    if (tid < RES) {
        float s = (tid + 0.5f) * (56.f / 64.f) - 0.5f;
        int fl = (int)floorf(s);
        float w[4]; float ws = 0.f;
        #pragma unroll
        for (int t = 0; t < 4; ++t) {
            int i = fl - 1 + t;
            float wv = keys_cubic(s - (float)i);
            if (i < 0 || i >= IN_HW) wv = 0.f;
            w[t] = wv; ws += wv;
            s_i[tid * 4 + t] = min(max(i, 0), IN_HW - 1);
        }
        float inv = 1.f / ws;
        #pragma unroll
        for (int t = 0; t < 4; ++t) s_w[tid * 4 + t] = w[t] * inv;
    }
    __syncthreads();

    // horizontal pass: tmp[y][ox]; a wave shares y, lanes span ox=0..63
    {
        const int ox = tid & 63, y0 = tid >> 6;
        const float w0 = s_w[ox * 4], w1 = s_w[ox * 4 + 1],
                    w2 = s_w[ox * 4 + 2], w3 = s_w[ox * 4 + 3];
        const int i0 = s_i[ox * 4], i1 = s_i[ox * 4 + 1],
                  i2 = s_i[ox * 4 + 2], i3 = s_i[ox * 4 + 3];
        for (int y = y0; y < IN_HW; y += 4) {
            const float* row = sm_in + y * IN_HW;
            sm_tmp[y * RES + ox] = w0 * row[i0] + w1 * row[i1] + w2 * row[i2] + w3 * row[i3];
        }
    }
    __syncthreads();

    // vertical pass + running argmax (first-index tie-break like jnp.argmax)
    float best = -INFINITY; int bidx = 0;
    for (int p = tid; p < RES * RES; p += 256) {
        const int oy = p >> 6, ox = p & 63;
        float v = s_w[oy * 4 + 0] * sm_tmp[s_i[oy * 4 + 0] * RES + ox]
                + s_w[oy * 4 + 1] * sm_tmp[s_i[oy * 4 + 1] * RES + ox]
                + s_w[oy * 4 + 2] * sm_tmp[s_i[oy * 4 + 2] * RES + ox]
                + s_w[oy * 4 + 3] * sm_tmp[s_i[oy * 4 + 3] * RES + ox];
        if (v > best) { best = v; bidx = p; }   // per-thread p increases -> earliest kept
    }
    #pragma unroll
    for (int off = 32; off; off >>= 1) {
        float ov = __shfl_down(best, off);
        int   oi = __shfl_down(bidx, off);
        if (ov > best || (ov == best && oi < bidx)) { best = ov; bidx = oi; }
    }
    const int wv = tid >> 6, ln = tid & 63;
    if (ln == 0) { s_red_v[wv] = best; s_red_i[wv] = bidx; }
    __syncthreads();
    if (tid == 0) {
        float bv = s_red_v[0]; int bi = s_red_i[0];
        #pragma unroll
        for (int w = 1; w < 4; ++w) {
            float v = s_red_v[w]; int i2 = s_red_i[w];
            if (v > bv || (v == bv && i2 < bi)) { bv = v; bi = i2; }
        }
        const int r = map_id / K_KP;
        const float x0 = rois[r * 4 + 0], y0r = rois[r * 4 + 1];
        const float x1 = rois[r * 4 + 2], y1r = rois[r * 4 + 3];
        const float wdt = fmaxf(x1 - x0, 1.f), hgt = fmaxf(y1r - y0r, 1.f);
        const float wc = wdt * (1.f / 64.f), hc = hgt * (1.f / 64.f);
        const int xi = bi & 63, yi = bi >> 6;
        float* xyp = out + 2 + (size_t)map_id * 3;
        xyp[0] = ((float)xi + 0.5f) * wc + x0;
        xyp[1] = ((float)yi + 0.5f) * hc + y0r;
        xyp[2] = 1.f;
        out[52226 + map_id] = bv;
    }
}

// ------------- mask: gather selected class, sigmoid, write (r,1,28,28) -------------
__global__ __launch_bounds__(256) void mask_kernel(
    const float* __restrict__ ml, const int* __restrict__ mlab,
    float* __restrict__ out)
{
    const int r = blockIdx.x, tid = threadIdx.x;
    const int lbl = mlab[r];
    const float2* src = (const float2*)(ml + ((size_t)r * N_CLS + lbl) * 784);
    float2* dst = (float2*)(out + 69634 + (size_t)r * 784);
    for (int i = tid; i < 392; i += 256) {
        float2 v = src[i];
        float2 o;
        o.x = 1.f / (1.f + expf(-v.x));
        o.y = 1.f / (1.f + expf(-v.y));
        dst[i] = o;
    }
}

extern "C" void kernel_launch(void* const* d_in, const int* in_sizes, int n_in,
                              void* d_out, int out_size, void* d_ws, size_t ws_size,
                              hipStream_t stream) {
    const float* class_logits = (const float*)d_in[0];
    const float* box_regression = (const float*)d_in[1];
    const int*   labels = (const int*)d_in[2];
    const float* regression_targets = (const float*)d_in[3];
    const float* kp_maps = (const float*)d_in[4];
    const float* kp_rois = (const float*)d_in[5];
    const float* mask_logits = (const float*)d_in[6];
    const int*   mask_labels = (const int*)d_in[7];
    float* out = (float*)d_out;

    // d_out is poisoned to 0xAA before each timed replay: zero the scalar slots.
    hipMemsetAsync(d_out, 0, 2 * sizeof(float), stream);

    loss_kernel<<<N_ROWS / 4, 256, 0, stream>>>(class_logits, box_regression,
                                                labels, regression_targets, out);
    kp_kernel<<<R_ROIS * K_KP, 256, 0, stream>>>(kp_maps, kp_rois, out);
    mask_kernel<<<R_ROIS, 256, 0, stream>>>(mask_logits, mask_labels, out);
}

// Round 2
// 539.952 us; speedup vs baseline: 1.0064x; 1.0064x over previous
//
#include <hip/hip_runtime.h>
#include <math.h>

#define RES 64
#define IN_HW 56
#define K_KP 17
#define N_ROWS 4096
#define N_CLS 91
#define R_ROIS 1024
#define SMOOTH_BETA (1.0f / 9.0f)

// Output layout (fp32 flat):
//   [0]                      cls_loss
//   [1]                      box_loss
//   [2 .. 2+52224)           xy_preds  (1024,17,3)
//   [52226 .. 52226+17408)   end_scores (1024,17)
//   [69634 .. 69634+802816)  mask_prob (1024,1,28,28)

__device__ __forceinline__ float keys_cubic(float x) {
    x = fabsf(x);
    if (x < 1.f) return ((1.5f * x - 2.5f) * x) * x + 1.f;
    if (x < 2.f) return ((-0.5f * x + 2.5f) * x - 4.f) * x + 2.f;
    return 0.f;
}

// floor((7*o - 0.5)/8) == (7*o - 1) >> 3 for integer o >= 0 (arith shift)
__device__ __forceinline__ int fl_of(int o) { return (7 * o - 1) >> 3; }

// ---------------- losses: 1 wave per row, 4 rows per block ----------------
__global__ __launch_bounds__(256) void loss_kernel(
    const float* __restrict__ logits, const float* __restrict__ boxreg,
    const int* __restrict__ labels, const float* __restrict__ tgt,
    float* __restrict__ out)
{
    __shared__ float s_cls[4], s_box[4];
    const int tid = threadIdx.x, wv = tid >> 6, ln = tid & 63;
    const int row = blockIdx.x * 4 + wv;

    const float* lr = logits + (size_t)row * N_CLS;
    float a = (ln < N_CLS) ? lr[ln] : -INFINITY;
    float b = (ln + 64 < N_CLS) ? lr[ln + 64] : -INFINITY;
    float m = fmaxf(a, b);
    #pragma unroll
    for (int off = 32; off; off >>= 1) m = fmaxf(m, __shfl_down(m, off));
    m = __shfl(m, 0);
    float e = 0.f;
    if (ln < N_CLS) e += expf(a - m);
    if (ln + 64 < N_CLS) e += expf(b - m);
    #pragma unroll
    for (int off = 32; off; off >>= 1) e += __shfl_down(e, off);
    if (ln == 0) {
        float lsm = m + logf(e);
        int lbl = labels[row];
        const float* sel = boxreg + (size_t)row * (4 * N_CLS) + lbl * 4;
        const float* tg = tgt + (size_t)row * 4;
        float s = 0.f;
        #pragma unroll
        for (int j = 0; j < 4; ++j) {
            float d = sel[j] - tg[j];
            float ad = fabsf(d);
            s += (ad < SMOOTH_BETA) ? (0.5f * d * d / SMOOTH_BETA)
                                    : (ad - 0.5f * SMOOTH_BETA);
        }
        s_cls[wv] = lsm - lr[lbl];
        s_box[wv] = (lbl > 0) ? s : 0.f;
    }
    __syncthreads();
    if (tid == 0) {
        float c = s_cls[0] + s_cls[1] + s_cls[2] + s_cls[3];
        float bx = s_box[0] + s_box[1] + s_box[2] + s_box[3];
        atomicAdd(&out[0], c * (1.f / (float)N_ROWS));
        atomicAdd(&out[1], bx * (1.f / (float)N_ROWS));
    }
}

// ------------- keypoints: 1 block per (r,k) map; bicubic 56->64 + argmax -------------
__global__ __launch_bounds__(256) void kp_kernel(
    const float* __restrict__ maps, const float* __restrict__ rois,
    float* __restrict__ out)
{
    __shared__ float  sm_in[IN_HW * IN_HW];   // 3136 f
    __shared__ float  sm_tmp[IN_HW * RES];    // 3584 f
    __shared__ float4 s_w4[RES];              // normalized 4-tap weights per output idx
    __shared__ float  s_red_v[4];
    __shared__ int    s_red_i[4];

    const int map_id = blockIdx.x;            // r*17 + k
    const int tid = threadIdx.x;

    // stage 56x56 map into LDS (float4, coalesced, 16B-aligned)
    {
        const float4* src = (const float4*)(maps + (size_t)map_id * (IN_HW * IN_HW));
        float4* dst = (float4*)sm_in;
        for (int i = tid; i < (IN_HW * IN_HW) / 4; i += 256) dst[i] = src[i];
    }

    // bicubic weights (JAX: half-pixel centers, Keys a=-0.5, OOR taps dropped + renorm)
    if (tid < RES) {
        float s = (tid + 0.5f) * (56.f / 64.f) - 0.5f;   // exact in fp32
        int fl = (int)floorf(s);
        float w[4]; float ws = 0.f;
        #pragma unroll
        for (int t = 0; t < 4; ++t) {
            int i = fl - 1 + t;
            float wv = keys_cubic(s - (float)i);
            if (i < 0 || i >= IN_HW) wv = 0.f;
            w[t] = wv; ws += wv;
        }
        float inv = 1.f / ws;
        s_w4[tid] = make_float4(w[0] * inv, w[1] * inv, w[2] * inv, w[3] * inv);
    }
    __syncthreads();

    // horizontal pass: wave shares y, lanes span ox; weights/indices hoisted
    {
        const int ox = tid & 63;
        const int fl = fl_of(ox);                         // -1..55
        const int i0 = max(fl - 1, 0);
        const int i1 = max(fl, 0);
        const int i2 = min(fl + 1, IN_HW - 1);
        const int i3 = min(fl + 2, IN_HW - 1);
        const float4 w = s_w4[ox];
        for (int y = tid >> 6; y < IN_HW; y += 4) {
            const float* row = sm_in + y * IN_HW;
            sm_tmp[y * RES + ox] = w.x * row[i0] + w.y * row[i1]
                                 + w.z * row[i2] + w.w * row[i3];
        }
    }
    __syncthreads();

    // vertical pass: lane = ox, 16 consecutive oy per wave; register sliding window
    float best = -INFINITY; int bidx = 0;
    {
        const int ox = tid & 63;
        const int oy0 = (tid >> 6) * 16;
        int fl = fl_of(oy0);
        #define CLAMP_ROW(i) (min(max((i), 0), IN_HW - 1))
        float r0 = sm_tmp[CLAMP_ROW(fl - 1) * RES + ox];
        float r1 = sm_tmp[CLAMP_ROW(fl    ) * RES + ox];
        float r2 = sm_tmp[CLAMP_ROW(fl + 1) * RES + ox];
        float r3 = sm_tmp[CLAMP_ROW(fl + 2) * RES + ox];
        #pragma unroll
        for (int k = 0; k < 16; ++k) {
            const int oy = oy0 + k;
            const float4 w = s_w4[oy];                    // broadcast b128
            float v = w.x * r0 + w.y * r1 + w.z * r2 + w.w * r3;
            if (v > best) { best = v; bidx = oy * RES + ox; }
            if (k < 15) {
                int nfl = fl_of(oy + 1);                  // wave-uniform branch
                if (nfl != fl) {
                    r0 = r1; r1 = r2; r2 = r3;
                    r3 = sm_tmp[CLAMP_ROW(nfl + 2) * RES + ox];
                    fl = nfl;
                }
            }
        }
        #undef CLAMP_ROW
    }
    #pragma unroll
    for (int off = 32; off; off >>= 1) {
        float ov = __shfl_down(best, off);
        int   oi = __shfl_down(bidx, off);
        if (ov > best || (ov == best && oi < bidx)) { best = ov; bidx = oi; }
    }
    const int wv = tid >> 6, ln = tid & 63;
    if (ln == 0) { s_red_v[wv] = best; s_red_i[wv] = bidx; }
    __syncthreads();
    if (tid == 0) {
        float bv = s_red_v[0]; int bi = s_red_i[0];
        #pragma unroll
        for (int w = 1; w < 4; ++w) {
            float v = s_red_v[w]; int i2 = s_red_i[w];
            if (v > bv || (v == bv && i2 < bi)) { bv = v; bi = i2; }
        }
        const int r = map_id / K_KP;
        const float x0 = rois[r * 4 + 0], y0r = rois[r * 4 + 1];
        const float x1 = rois[r * 4 + 2], y1r = rois[r * 4 + 3];
        const float wdt = fmaxf(x1 - x0, 1.f), hgt = fmaxf(y1r - y0r, 1.f);
        const float wc = wdt * (1.f / 64.f), hc = hgt * (1.f / 64.f);
        const int xi = bi & 63, yi = bi >> 6;
        float* xyp = out + 2 + (size_t)map_id * 3;
        xyp[0] = ((float)xi + 0.5f) * wc + x0;
        xyp[1] = ((float)yi + 0.5f) * hc + y0r;
        xyp[2] = 1.f;
        out[52226 + map_id] = bv;
    }
}

// ------------- mask: gather selected class, sigmoid, write (r,1,28,28) -------------
__global__ __launch_bounds__(256) void mask_kernel(
    const float* __restrict__ ml, const int* __restrict__ mlab,
    float* __restrict__ out)
{
    const int r = blockIdx.x, tid = threadIdx.x;
    const int lbl = mlab[r];
    const float2* src = (const float2*)(ml + ((size_t)r * N_CLS + lbl) * 784);
    float2* dst = (float2*)(out + 69634 + (size_t)r * 784);
    for (int i = tid; i < 392; i += 256) {
        float2 v = src[i];
        float2 o;
        o.x = 1.f / (1.f + expf(-v.x));
        o.y = 1.f / (1.f + expf(-v.y));
        dst[i] = o;
    }
}

extern "C" void kernel_launch(void* const* d_in, const int* in_sizes, int n_in,
                              void* d_out, int out_size, void* d_ws, size_t ws_size,
                              hipStream_t stream) {
    const float* class_logits = (const float*)d_in[0];
    const float* box_regression = (const float*)d_in[1];
    const int*   labels = (const int*)d_in[2];
    const float* regression_targets = (const float*)d_in[3];
    const float* kp_maps = (const float*)d_in[4];
    const float* kp_rois = (const float*)d_in[5];
    const float* mask_logits = (const float*)d_in[6];
    const int*   mask_labels = (const int*)d_in[7];
    float* out = (float*)d_out;

    // d_out is poisoned to 0xAA before each timed replay: zero the scalar loss slots.
    hipMemsetAsync(d_out, 0, 2 * sizeof(float), stream);

    loss_kernel<<<N_ROWS / 4, 256, 0, stream>>>(class_logits, box_regression,
                                                labels, regression_targets, out);
    kp_kernel<<<R_ROIS * K_KP, 256, 0, stream>>>(kp_maps, kp_rois, out);
    mask_kernel<<<R_ROIS, 256, 0, stream>>>(mask_logits, mask_labels, out);
}